// Round 7
// baseline (265.652 us; speedup 1.0000x reference)
//
#include <hip/hip_runtime.h>

#define B_    64
#define CIN_  3
#define HW_   64
#define HID_  128
#define K_    1024
#define H1_   31      // after conv1 (stride2 k4)
#define H2_   30      // after conv2 (stride1 k2)
#define NROWS_ 57600  // B_*H2_*H2_
#define NELEM_ 7372800

typedef __bf16 bf16_t;
typedef __attribute__((ext_vector_type(8))) __bf16 bf16x8;
typedef __attribute__((ext_vector_type(4))) float f32x4;
typedef __attribute__((ext_vector_type(16))) float f32x16;

__device__ __forceinline__ void gload_lds16(const void* g, void* l) {
  __builtin_amdgcn_global_load_lds(
      (const __attribute__((address_space(1))) unsigned int*)g,
      (__attribute__((address_space(3))) unsigned int*)l, 16, 0, 0);
}

// ---------------- wprep: all weight transposes + codebook prep --------------
__global__ __launch_bounds__(256) void wprep_k(const float* __restrict__ ew1,
    const float* __restrict__ ew2, const float* __restrict__ dw1,
    const float* __restrict__ dw2, const float* __restrict__ cb,
    bf16_t* __restrict__ wc1, bf16_t* __restrict__ wc2,
    bf16_t* __restrict__ wd1, bf16_t* __restrict__ wt2,
    bf16_t* __restrict__ cbb, float* __restrict__ cnorm,
    unsigned* __restrict__ hist, float* __restrict__ sse) {
  int id = blockIdx.x * 256 + threadIdx.x;                // grid 256 -> 65536
  int t = id >> 14, co = (id >> 7) & 127, ci = id & 127;
  wc2[id] = (bf16_t)ew2[(co * 128 + ci) * 4 + t];
  wd1[id] = (bf16_t)dw1[(ci * 128 + co) * 4 + (3 - t)];
  if (id < 8192) {
    int n = id >> 9, k = id & 511;
    int tap = k >> 7, c = k & 127;
    if (n < 12) {
      int nco = n >> 2, ph = (n >> 1) & 1, pw = n & 1;
      int off = (tap >> 1) * 8 + (tap & 1) * 2;           // 0,2,8,10
      wt2[id] = (bf16_t)dw2[c * 48 + nco * 16 + ph * 4 + pw + off];
    } else {
      wt2[id] = (bf16_t)0.f;
    }
    int c1 = id >> 6, k1 = id & 63;                       // wc1
    wc1[id] = (bf16_t)(k1 < 48 ? ew1[c1 * 48 + k1] : 0.f);
  }
  if (id < K_) {
    float s0 = 0.f;
    for (int d = 0; d < HID_; d += 4) {
      float4 v = *(const float4*)&cb[id * HID_ + d];
      bf16_t tt[4] = {(bf16_t)v.x, (bf16_t)v.y, (bf16_t)v.z, (bf16_t)v.w};
      *(ushort4*)&((ushort*)cbb)[id * HID_ + d] = *(ushort4*)tt;
      float f0 = (float)tt[0], f1 = (float)tt[1];
      float f2 = (float)tt[2], f3 = (float)tt[3];
      s0 += f0 * f0 + f1 * f1 + f2 * f2 + f3 * f3;
    }
    cnorm[id] = s0;
    hist[id] = 0u;
  }
  if (id == 0) *sse = 0.f;
}

// ---------------- conv1 (MFMA, fused transpose): x -> relu -> z1t bf16 ------
__global__ __launch_bounds__(256, 2) void conv1m_k(const float* __restrict__ x,
    const bf16_t* __restrict__ wc1, const float* __restrict__ bias,
    ushort* __restrict__ z1t) {
  __shared__ __align__(16) bf16_t as_[64 * 72];           // 9 KB
  __shared__ __align__(16) bf16_t bs_[128 * 72];          // 18 KB
  int b = blockIdx.x >> 4, rt = blockIdx.x & 15;          // grid = 64*16
  int tid = threadIdx.x, wv = tid >> 6, ln = tid & 63;
  const float* xb = x + (size_t)b * 12288;
  #pragma unroll
  for (int it = 0; it < 16; ++it) {
    int e = it * 256 + tid;                               // 4096 A entries
    int p = e >> 6, k = e & 63;
    float v = 0.f;
    if (k < 48) {
      int ci = k >> 4, kh = (k >> 2) & 3, kw = k & 3;
      int row = 2 * rt + (p >> 5); if (row > 30) row = 30; // clamp: discarded
      int col = p & 31;            if (col > 30) col = 30;
      v = xb[ci * 4096 + (2 * row + kh) * 64 + 2 * col + kw];
    }
    as_[p * 72 + k] = (bf16_t)v;
  }
  {
    const float4* wg = (const float4*)wc1;
    #pragma unroll
    for (int it = 0; it < 4; ++it) {
      int fi = it * 256 + tid;                            // 1024 f4s
      int co = fi >> 3, k8 = fi & 7;
      *(float4*)&bs_[co * 72 + k8 * 8] = wg[fi];
    }
  }
  __syncthreads();
  int q = ln >> 4, l = ln & 15;
  f32x4 acc8[8];
  #pragma unroll
  for (int c = 0; c < 8; ++c) acc8[c] = (f32x4){0.f, 0.f, 0.f, 0.f};
  bf16x8 af[2];
  #pragma unroll
  for (int kk = 0; kk < 2; ++kk)
    af[kk] = *(const bf16x8*)&as_[(wv * 16 + l) * 72 + kk * 32 + q * 8];
  #pragma unroll
  for (int cot = 0; cot < 8; ++cot) {
    #pragma unroll
    for (int kk = 0; kk < 2; ++kk) {
      bf16x8 bf = *(const bf16x8*)&bs_[(cot * 16 + l) * 72 + kk * 32 + q * 8];
      acc8[cot] = __builtin_amdgcn_mfma_f32_16x16x32_bf16(af[kk], bf,
                                                          acc8[cot], 0, 0, 0);
    }
  }
  #pragma unroll
  for (int cot = 0; cot < 8; ++cot) {
    int co = cot * 16 + l;
    float bv = bias[co];
    #pragma unroll
    for (int r = 0; r < 4; ++r) {
      int pos = wv * 16 + q * 4 + r;
      int prow = 2 * rt + (pos >> 5), pcol = pos & 31;
      if (prow < 31 && pcol < 31) {
        float v = fmaxf(acc8[cot][r] + bv, 0.f);
        bf16_t h = (bf16_t)v;
        z1t[((size_t)(b * 1024 + prow * 32 + pcol)) * 128 + co] = *(ushort*)&h;
      }
    }
  }
}

// ---------------- conv2 (MFMA, B in LDS): z1t -> relu -> zbuf bf16 only -----
__global__ __launch_bounds__(256, 2) void conv2m_k(const bf16_t* __restrict__ z1t,
    const bf16_t* __restrict__ wc2, const float* __restrict__ bias,
    ushort* __restrict__ zbuf) {
  __shared__ __align__(16) bf16_t as_[98 * 136];          // rows m+off, off<=33
  __shared__ __align__(16) bf16_t bs_[128 * 136];
  int blk = blockIdx.x;                                   // 64*15
  int b = blk / 15, rt = blk % 15;
  int tid = threadIdx.x, wv = tid >> 6, ln = tid & 63;
  const float4* src = (const float4*)(z1t + ((size_t)b * 1024 + rt * 64) * 128);
  #pragma unroll
  for (int s = 0; s < 7; ++s) {
    int f = s * 256 + tid;                                // 98*16 = 1568 f4s
    if (f < 1568) {
      int lp = f >> 4, c16 = f & 15;                      // max row 993 < 1024
      *(float4*)&as_[lp * 136 + c16 * 8] = src[f];
    }
  }
  int m = wv * 16 + (ln & 15), q = ln >> 4;
  f32x4 acc8[8];
  #pragma unroll
  for (int c = 0; c < 8; ++c) acc8[c] = (f32x4){0.f, 0.f, 0.f, 0.f};
  const float4* w4 = (const float4*)wc2;
  #pragma unroll
  for (int t = 0; t < 4; ++t) {
    __syncthreads();                                      // bs_ reuse (+A 1st)
    #pragma unroll
    for (int s = 0; s < 8; ++s) {
      int f = s * 256 + tid;
      int co = f >> 4, c16 = f & 15;
      *(float4*)&bs_[co * 136 + c16 * 8] = w4[t * 2048 + f];
    }
    __syncthreads();
    int off = (t >> 1) * 32 + (t & 1);                    // tap offset in pos
    bf16x8 af[4];
    #pragma unroll
    for (int kk = 0; kk < 4; ++kk)
      af[kk] = *(const bf16x8*)&as_[(m + off) * 136 + kk * 32 + q * 8];
    #pragma unroll
    for (int cot = 0; cot < 8; ++cot) {
      #pragma unroll
      for (int kk = 0; kk < 4; ++kk) {
        bf16x8 bf = *(const bf16x8*)&bs_[(cot * 16 + (ln & 15)) * 136 +
                                         kk * 32 + q * 8];
        acc8[cot] = __builtin_amdgcn_mfma_f32_16x16x32_bf16(af[kk], bf,
                                                            acc8[cot], 0, 0, 0);
      }
    }
  }
  #pragma unroll
  for (int cot = 0; cot < 8; ++cot) {
    int co = cot * 16 + (ln & 15);
    float bv = bias[co];
    #pragma unroll
    for (int r = 0; r < 4; ++r) {
      int mo = wv * 16 + q * 4 + r;
      int ocol = mo & 31;
      if (ocol < 30) {
        int orow = rt * 2 + (mo >> 5);                    // always < 30
        float v = fmaxf(acc8[cot][r] + bv, 0.f);
        bf16_t h = (bf16_t)v;
        zbuf[(size_t)(b * HID_ + co) * 900 + orow * 30 + ocol] = *(ushort*)&h;
      }
    }
  }
}

// ---------------- VQ phase 1 (MFMA 32x32x16): split-code partial argmax -----
// r27: TLP attack.  All prior variants (r20..r26) land 59-100us with
// MFMA/VALU/HBM all <30% and Occ 13-17% -- latency-bound with only 900
// blocks (3.5/CU of work, no churn).  Split the CODE axis across blocks:
// grid = 900 rowblocks x 4 slices = 3600 blocks (14/CU of work).  Each
// block scans 64 rows x 256 codes using r25's proven internals (gload_lds
// + XOR swizzle, dbuf, 64-code chunks, lean ~72-80 VGPR, LDS ~34 KB -> 4
// blocks/CU by both VGPR and LDS).  Block writes per-slice partial
// (score,idx); vqr_k reduces 4 slices/row + hist + fused SSE.  Tie
// semantics exact: ascending within slice (strict >), cross-slice
// (score,idx) compare smaller-idx-wins.
// C/D: col(code)=lane&31, row=(reg&3)+8*(reg>>2)+4*(lane>>5)  [m74/m101].
__global__ __launch_bounds__(256, 2) void vq1_k(const bf16_t* __restrict__ zb,
    const bf16_t* __restrict__ cbb, const float* __restrict__ cnorm,
    float* __restrict__ pscore, int* __restrict__ pidx) {
  __shared__ __align__(16) bf16_t cbs[2][64 * 128];       // 2 x 16 KB linear
  __shared__ float cns_s[256];                            // slice -0.5*|c|^2
  __shared__ float redS[2][64];
  __shared__ int   redI[2][64];
  int bid = blockIdx.x;                                   // 3600 = 900 rb x 4
  int slice = bid & 3, rb = bid >> 2;
  int n0 = rb * 64;
  int tid = threadIdx.x;
  int wv = tid >> 6, ln = tid & 63;
  int lr = ln & 31, lh = ln >> 5;
  int mt = wv & 1, pt = wv >> 1;                          // m-tile / code-tile
  int rr = pt * 32 + lr;                                  // code row in chunk
  const char* cbBase = (const char*)cbb + (size_t)slice * 65536;

  // stage chunk c (16 KB) into buf: dest linear byte D = i*4096 + tid*16,
  // source = chunk + (D ^ ((row&15)<<4)), row = D>>8.  Wave-uniform LDS base.
#define STAGE_(buf, c)                                                       \
  {                                                                          \
    const char* gsrc_ = cbBase + (size_t)(c) * 16384;                        \
    char* lb_ = (char*)&cbs[buf][0] + (tid >> 6) * 1024;                     \
    _Pragma("unroll")                                                        \
    for (int i_ = 0; i_ < 4; ++i_) {                                         \
      int D_ = i_ * 4096 + tid * 16;                                         \
      int so_ = D_ ^ (((D_ >> 8) & 15) << 4);                                \
      gload_lds16(gsrc_ + so_, lb_ + i_ * 4096);                             \
    }                                                                        \
  }

  STAGE_(0, 0);
  if (tid < 64) {                                         // slice cns (256 f)
    float4 cv = ((const float4*)(cnorm + slice * 256))[tid];
    cv.x *= -0.5f; cv.y *= -0.5f; cv.z *= -0.5f; cv.w *= -0.5f;
    ((float4*)cns_s)[tid] = cv;
  }
  // hoisted A fragments (rows n0 + mt*32 + lr), direct from L2
  const ushort* za = (const ushort*)zb +
                     ((size_t)(n0 + mt * 32 + lr)) * 128 + lh * 8;
  bf16x8 af[8];
  #pragma unroll
  for (int ks = 0; ks < 8; ++ks) af[ks] = *(const bf16x8*)(za + ks * 16);
  // per-lane swizzled B-frag byte offsets (loop-invariant)
  int off8[8];
  #pragma unroll
  for (int ks = 0; ks < 8; ++ks)
    off8[ks] = rr * 256 + ((lh * 16 + ks * 32) ^ ((rr & 15) << 4));
  float bS[16];
  int   bI[16];
  #pragma unroll
  for (int r = 0; r < 16; ++r) { bS[r] = -3.4e38f; bI[r] = 0; }

#define COMPUTE_(buf, c)                                                     \
  {                                                                          \
    int code_ = slice * 256 + (c) * 64 + rr;                                 \
    float hv_ = cns_s[(c) * 64 + rr];                                        \
    f32x16 acc_;                                                             \
    _Pragma("unroll")                                                        \
    for (int r_ = 0; r_ < 16; ++r_) acc_[r_] = hv_;                          \
    _Pragma("unroll")                                                        \
    for (int ks_ = 0; ks_ < 8; ++ks_) {                                      \
      bf16x8 bfr_ = *(const bf16x8*)((const char*)&cbs[buf][0] + off8[ks_]); \
      acc_ = __builtin_amdgcn_mfma_f32_32x32x16_bf16(af[ks_], bfr_, acc_,    \
                                                     0, 0, 0);               \
    }                                                                        \
    _Pragma("unroll")                                                        \
    for (int r_ = 0; r_ < 16; ++r_)                                          \
      if (acc_[r_] > bS[r_]) { bS[r_] = acc_[r_]; bI[r_] = code_; }          \
  }

  __syncthreads();                                        // chunk0 + cns ready
  STAGE_(1, 1);
  COMPUTE_(0, 0);
  __syncthreads();                            // chunk1 staged; buf0 free
  STAGE_(0, 2);
  COMPUTE_(1, 1);
  __syncthreads();                            // chunk2 staged; buf1 free
  STAGE_(1, 3);
  COMPUTE_(0, 2);
  __syncthreads();                            // chunk3 staged
  COMPUTE_(1, 3);
  // reduce across the 32 code-lanes of each half; rows stay per-lane
  #pragma unroll
  for (int r = 0; r < 16; ++r) {
    float s = bS[r]; int i = bI[r];
    #pragma unroll
    for (int o = 16; o > 0; o >>= 1) {
      float os = __shfl_xor(s, o, 64); int oi = __shfl_xor(i, o, 64);
      if (os > s || (os == s && oi < i)) { s = os; i = oi; }
    }
    bS[r] = s; bI[r] = i;
  }
  if (lr == 0) {
    #pragma unroll
    for (int r = 0; r < 16; ++r) {
      int row = (r & 3) + 8 * (r >> 2) + 4 * lh;          // C/D row mapping
      redS[pt][mt * 32 + row] = bS[r];
      redI[pt][mt * 32 + row] = bI[r];
    }
  }
  __syncthreads();
  if (tid < 64) {                                         // row = n0 + tid
    float s0 = redS[0][tid], s1 = redS[1][tid];
    int i0 = redI[0][tid], i1 = redI[1][tid];
    bool t = (s1 > s0) || (s1 == s0 && i1 < i0);
    pscore[slice * NROWS_ + n0 + tid] = t ? s1 : s0;
    pidx[slice * NROWS_ + n0 + tid] = t ? i1 : i0;
  }
#undef STAGE_
#undef COMPUTE_
}

// ---------------- VQ reduce: 4 slices -> idx + hist + fused SSE -------------
__global__ __launch_bounds__(256) void vqr_k(const bf16_t* __restrict__ zb,
    const float* __restrict__ pscore, const int* __restrict__ pidx,
    int* __restrict__ idxArr, unsigned* __restrict__ hist,
    float* __restrict__ sse) {
  int n = blockIdx.x * 256 + threadIdx.x;                 // grid 225 -> 57600
  float s = pscore[n]; int bi = pidx[n];
  #pragma unroll
  for (int sl = 1; sl < 4; ++sl) {
    float os = pscore[sl * NROWS_ + n]; int oi = pidx[sl * NROWS_ + n];
    if (os > s || (os == s && oi < bi)) { s = os; bi = oi; }
  }
  idxArr[n] = bi;
  atomicAdd(&hist[bi], 1u);
  // fused SSE: dist = |z|^2 - 2*score  (score includes -0.5|c|^2)
  const ushort* zr = (const ushort*)zb + (size_t)n * 128;
  float zn = 0.f;
  #pragma unroll
  for (int sg = 0; sg < 16; ++sg) {
    bf16x8 v = *(const bf16x8*)(zr + sg * 8);
    #pragma unroll
    for (int e = 0; e < 8; ++e) {
      float fv = (float)v[e];
      zn = fmaf(fv, fv, zn);
    }
  }
  float se = zn - 2.f * s;
  #pragma unroll
  for (int o = 32; o > 0; o >>= 1) se += __shfl_down(se, o, 64);
  if ((threadIdx.x & 63) == 0) atomicAdd(sse, se);
}

// ---------------- tqz: tq gather + qt pad zero ------------------------------
__global__ __launch_bounds__(256) void tqz_k(const bf16_t* __restrict__ cbb,
    const int* __restrict__ idxArr, ushort* __restrict__ qt) {
  __shared__ ushort t[60 * 128];                          // 15 KB
  int bid = blockIdx.x, tid = threadIdx.x;
  if (bid < 960) {                                        // ---- tq ----
    int b = bid / 15, st = bid % 15;                      // 60-s tile
    int s0 = st * 60;
    #pragma unroll
    for (int it = 0; it < 8; ++it) {
      int task = it * 256 + tid;                          // sc*128 + c
      if (task < 1920) {
        int sc = task >> 7, c = task & 127;
        int f = b * 115200 + c * 900 + s0 + sc * 4;
        int n = f >> 7, d = f & 127;                      // d%4==0, no wrap
        int k = idxArr[n];
        ushort4 v = *(const ushort4*)((const ushort*)cbb + k * 128 + d);
        t[(sc * 4 + 0) * 128 + c] = v.x;
        t[(sc * 4 + 1) * 128 + c] = v.y;
        t[(sc * 4 + 2) * 128 + c] = v.z;
        t[(sc * 4 + 3) * 128 + c] = v.w;
      }
    }
    __syncthreads();
    #pragma unroll
    for (int it = 0; it < 4; ++it) {
      int task = it * 256 + tid;                          // sl*16 + c16
      if (task < 960) {
        int sl = task >> 4, c16 = task & 15;
        int s = s0 + sl;
        int h = s / 30, w = s - h * 30;
        int p = (h + 1) * 32 + (w + 1);
        *(uint4*)&qt[((size_t)(b * 1024 + p)) * 128 + c16 * 8] =
            *(uint4*)&t[sl * 128 + c16 * 8];
      }
    }
  } else {                                                // ---- qt pad ----
    int zb_ = (bid - 960) * 4;                            // 4 b's per block
    uint4 zz = {0u, 0u, 0u, 0u};
    for (int e = tid; e < 4 * 124 * 16; e += 256) {
      int bb = zb_ + e / (124 * 16);
      int rem = e % (124 * 16);
      int pe = rem >> 4, s16 = rem & 15;
      int p;
      if (pe < 32) p = pe;                                // row 0
      else if (pe < 64) p = 31 * 32 + (pe - 32);          // row 31
      else {
        int idx = pe - 64;                                // rows 1..30, c 0/31
        p = (1 + (idx >> 1)) * 32 + ((idx & 1) ? 31 : 0);
      }
      *(uint4*)&qt[((size_t)(bb * 1024 + p)) * 128 + s16 * 8] = zz;
    }
  }
}

// ---------------- convT1 (MFMA, B in LDS): qt -> relu -> yt bf16 ------------
__global__ __launch_bounds__(256, 2) void convt1m_k(const bf16_t* __restrict__ qt,
    const bf16_t* __restrict__ wd1, const float* __restrict__ bias,
    ushort* __restrict__ yt) {
  __shared__ __align__(16) bf16_t as_[98 * 136];
  __shared__ __align__(16) bf16_t bs_[128 * 136];
  int blk = blockIdx.x;                                   // 64*16
  int b = blk >> 4, rt = blk & 15;
  int tid = threadIdx.x, wv = tid >> 6, ln = tid & 63;
  {                                                       // fused pad zeroing
    uint4 zz = {0u, 0u, 0u, 0u};
    ushort* ytb = yt + (size_t)b * 1156 * 128;
    int nrows = (rt < 15) ? 2 : 1;                        // rt=15 owns row 31
    int r0 = 2 * rt + 1;
    for (int e = tid; e < nrows * 48; e += 256) {         // cols 0,32,33
      int rr = e / 48, rem = e % 48, cc = rem / 16, s16 = rem % 16;
      int col = (cc == 0) ? 0 : (cc == 1 ? 32 : 33);
      *(uint4*)&ytb[((size_t)((r0 + rr) * 34 + col)) * 128 + s16 * 8] = zz;
    }
    if (rt == 0)
      for (int e = tid; e < 34 * 16; e += 256)            // row 0
        *(uint4*)&ytb[((size_t)(e >> 4)) * 128 + (e & 15) * 8] = zz;
    if (rt == 15)
      for (int e = tid; e < 2 * 34 * 16; e += 256) {      // rows 32,33
        int rr = 32 + e / 544, rem = e % 544;
        *(uint4*)&ytb[((size_t)(rr * 34 + (rem >> 4))) * 128 + (rem & 15) * 8]
            = zz;
      }
  }
  const float4* src = (const float4*)(qt + (size_t)b * 1024 * 128);
  #pragma unroll
  for (int s = 0; s < 7; ++s) {
    int f = s * 256 + tid;                                // 1568 f4s
    if (f < 1568) {
      int lp = f >> 4, c16 = f & 15;
      int gr = rt * 64 + lp;
      if (gr > 1023) gr = 1023;                           // rt=15 guard
      *(float4*)&as_[lp * 136 + c16 * 8] = src[gr * 16 + c16];
    }
  }
  int m = wv * 16 + (ln & 15), q = ln >> 4;
  f32x4 acc8[8];
  #pragma unroll
  for (int c = 0; c < 8; ++c) acc8[c] = (f32x4){0.f, 0.f, 0.f, 0.f};
  const float4* w4 = (const float4*)wd1;
  #pragma unroll
  for (int t = 0; t < 4; ++t) {
    __syncthreads();
    #pragma unroll
    for (int s = 0; s < 8; ++s) {
      int f = s * 256 + tid;
      int co = f >> 4, c16 = f & 15;
      *(float4*)&bs_[co * 136 + c16 * 8] = w4[t * 2048 + f];
    }
    __syncthreads();
    int off = (t >> 1) * 32 + (t & 1);
    bf16x8 af[4];
    #pragma unroll
    for (int kk = 0; kk < 4; ++kk)
      af[kk] = *(const bf16x8*)&as_[(m + off) * 136 + kk * 32 + q * 8];
    #pragma unroll
    for (int cot = 0; cot < 8; ++cot) {
      #pragma unroll
      for (int kk = 0; kk < 4; ++kk) {
        bf16x8 bf = *(const bf16x8*)&bs_[(cot * 16 + (ln & 15)) * 136 +
                                         kk * 32 + q * 8];
        acc8[cot] = __builtin_amdgcn_mfma_f32_16x16x32_bf16(af[kk], bf,
                                                            acc8[cot], 0, 0, 0);
      }
    }
  }
  #pragma unroll
  for (int cot = 0; cot < 8; ++cot) {
    int co = cot * 16 + (ln & 15);
    float bv = bias[co];
    #pragma unroll
    for (int r = 0; r < 4; ++r) {
      int mo = wv * 16 + q * 4 + r;
      int orow = rt * 2 + (mo >> 5), ocol = mo & 31;
      if (orow < 31 && ocol < 31) {
        float v = fmaxf(acc8[cot][r] + bv, 0.f);
        bf16_t h = (bf16_t)v;
        yt[((size_t)b * 1156 + (orow + 1) * 34 + (ocol + 1)) * 128 + co] =
            *(ushort*)&h;
      }
    }
  }
}

// ---------------- convT2 (MFMA): yt -> out fp32, + fused finalize -----------
__global__ __launch_bounds__(256, 2) void convt2m_k(const bf16_t* __restrict__ yt,
    const bf16_t* __restrict__ wt2, const float* __restrict__ bias,
    const unsigned* __restrict__ hist, const float* __restrict__ sse,
    float* __restrict__ out) {
  __shared__ __align__(16) bf16_t as_[128 * 136];         // 34.8 KB
  __shared__ float redf[256];                             // 1 KB (fin branch)
  int b = blockIdx.x >> 4, rt = blockIdx.x & 15;          // grid = 64*16
  int tid = threadIdx.x, wv = tid >> 6, ln = tid & 63;
  const float4* src = (const float4*)(yt + ((size_t)b * 1156 + rt * 68) * 128);
  #pragma unroll
  for (int s = 0; s < 8; ++s) {
    int f = s * 256 + tid;
    int lp = f >> 4, c16 = f & 15;
    *(float4*)&as_[lp * 136 + c16 * 8] = src[f];
  }
  __syncthreads();
  int mloc = wv * 16 + (ln & 15), q = ln >> 4;
  int qh = mloc >> 5, qw = mloc & 31;                     // local quadrant pos
  int base = (qh + 1) * 34 + qw + 1;                      // in staged window
  f32x4 acc = {0.f, 0.f, 0.f, 0.f};
  #pragma unroll
  for (int kc = 0; kc < 16; ++kc) {
    int tap = kc >> 2;
    int toff = (tap & 1) + (tap >> 1) * 34;               // 0,1,34,35
    bf16x8 af = *(const bf16x8*)&as_[(base - toff) * 136 +
                                     (kc & 3) * 32 + q * 8];
    bf16x8 bf = *(const bf16x8*)&wt2[(size_t)(ln & 15) * 512 + kc * 32 + q * 8];
    acc = __builtin_amdgcn_mfma_f32_16x16x32_bf16(af, bf, acc, 0, 0, 0);
  }
  __syncthreads();                                        // as_ reads done
  float* bb = (float*)as_;                                // bounce: 64x16 f32
  #pragma unroll
  for (int r = 0; r < 4; ++r)
    bb[(wv * 16 + q * 4 + r) * 16 + (ln & 15)] = acc[r];
  __syncthreads();
  if (tid < 192) {
    int row_id = tid >> 4;                                // co*4 + ohoff
    int co = row_id >> 2, ohoff = row_id & 3;
    int qhl = ohoff >> 1, ph = ohoff & 1;
    float bv = bias[co];
    int ow0 = (tid & 15) * 4;
    float tmp[4];
    #pragma unroll
    for (int e = 0; e < 4; ++e) {
      int ow = ow0 + e;
      tmp[e] = bb[(qhl * 32 + (ow >> 1)) * 16 + co * 4 + ph * 2 + (ow & 1)]
               + bv;
    }
    *(float4*)&out[((size_t)(b * 3 + co)) * 4096 + (rt * 4 + ohoff) * 64 + ow0]
        = *(float4*)tmp;
  }
  if (blockIdx.x == 0) {                                  // ---- fused fin ----
    float e = 0.f;
    for (int k = tid; k < K_; k += 256) {
      float p = (float)hist[k] * (1.0f / (float)NROWS_);
      e += p * logf(p + 1e-10f);
    }
    redf[tid] = e;
    __syncthreads();
    #pragma unroll
    for (int t = 128; t > 0; t >>= 1) {
      if (tid < t) redf[tid] += redf[tid + t];
      __syncthreads();
    }
    if (tid == 0) {
      out[786432] = 1.25f * (*sse) * (1.0f / (float)NELEM_);
      out[786433] = expf(-redf[0]);
    }
  }
}

extern "C" void kernel_launch(void* const* d_in, const int* in_sizes, int n_in,
                              void* d_out, int out_size, void* d_ws,
                              size_t ws_size, hipStream_t stream) {
  (void)in_sizes; (void)n_in; (void)out_size; (void)ws_size;
  const float* x   = (const float*)d_in[0];
  const float* ew1 = (const float*)d_in[1];
  const float* eb1 = (const float*)d_in[2];
  const float* ew2 = (const float*)d_in[3];
  const float* eb2 = (const float*)d_in[4];
  const float* cb  = (const float*)d_in[5];
  const float* dw1 = (const float*)d_in[6];
  const float* db1 = (const float*)d_in[7];
  const float* dw2 = (const float*)d_in[8];
  const float* db2 = (const float*)d_in[9];
  float* out = (float*)d_out;
  char* ws = (char*)d_ws;

  // ws layout (~97.5 MB, aliased by liveness):
  //  [0, 35,684,352)            yt bf16 18.94 MB (pad zeroed in convt1m)
  //  [35,684,352, 37,527,552)   pscore/pidx partials (vq1 -> vqr; dead before
  //                             convt1m writes yt, which ends at 18.9 MB)
  //  [65,175,552, 81,985,536)   z1t bf16 (conv1m->conv2m) then qt bf16
  //  [81,985,536, 96,731,136)   zbuf bf16 (conv2m->vq1)
  //  [96,731,136 ..)  cbb | wc2 | wd1 | idxArr | hist | cnorm | sse | wt2 | wc1
  ushort*   yt    = (ushort*)(ws);
  float*    pscore= (float*)(ws + 35684352);              // 4*57600*4 = 921600
  int*      pidx  = (int*)(ws + 36605952);                // 921600
  bf16_t*   z1t   = (bf16_t*)(ws + 65175552);
  bf16_t*   qt    = (bf16_t*)(ws + 65175552);
  ushort*   zbuf  = (ushort*)(ws + 81985536);
  bf16_t*   cbb   = (bf16_t*)(ws + 96731136);
  bf16_t*   wc2   = (bf16_t*)(ws + 96993280);
  bf16_t*   wd1   = (bf16_t*)(ws + 97124352);
  int*      idxArr= (int*)(ws + 97255424);
  unsigned* hist  = (unsigned*)(ws + 97485824);
  float*    cnorm = (float*)(ws + 97489920);
  float*    sse   = (float*)(ws + 97494016);
  bf16_t*   wt2   = (bf16_t*)(ws + 97497088);
  bf16_t*   wc1   = (bf16_t*)(ws + 97513472);

  wprep_k<<<dim3(256), dim3(256), 0, stream>>>(ew1, ew2, dw1, dw2, cb,
                                               wc1, wc2, wd1, wt2,
                                               cbb, cnorm, hist, sse);
  conv1m_k<<<dim3(1024), dim3(256), 0, stream>>>(x, wc1, eb1, (ushort*)z1t);
  conv2m_k<<<dim3(960), dim3(256), 0, stream>>>(z1t, wc2, eb2, zbuf);
  vq1_k<<<dim3(3600), dim3(256), 0, stream>>>((const bf16_t*)zbuf, cbb, cnorm,
                                              pscore, pidx);
  vqr_k<<<dim3(225), dim3(256), 0, stream>>>((const bf16_t*)zbuf, pscore, pidx,
                                             idxArr, hist, sse);
  tqz_k<<<dim3(976), dim3(256), 0, stream>>>(cbb, idxArr, (ushort*)qt);
  convt1m_k<<<dim3(1024), dim3(256), 0, stream>>>(qt, wd1, db1, yt);
  convt2m_k<<<dim3(1024), dim3(256), 0, stream>>>((const bf16_t*)yt, wt2, db2,
                                                  hist, sse, out);
}

// Round 8
// 234.145 us; speedup vs baseline: 1.1346x; 1.1346x over previous
//
#include <hip/hip_runtime.h>

#define B_    64
#define CIN_  3
#define HW_   64
#define HID_  128
#define K_    1024
#define H1_   31      // after conv1 (stride2 k4)
#define H2_   30      // after conv2 (stride1 k2)
#define NROWS_ 57600  // B_*H2_*H2_
#define NELEM_ 7372800

typedef __bf16 bf16_t;
typedef __attribute__((ext_vector_type(8))) __bf16 bf16x8;
typedef __attribute__((ext_vector_type(4))) float f32x4;
typedef __attribute__((ext_vector_type(16))) float f32x16;

// ---------------- wprep: all weight transposes + codebook prep --------------
__global__ __launch_bounds__(256) void wprep_k(const float* __restrict__ ew1,
    const float* __restrict__ ew2, const float* __restrict__ dw1,
    const float* __restrict__ dw2, const float* __restrict__ cb,
    bf16_t* __restrict__ wc1, bf16_t* __restrict__ wc2,
    bf16_t* __restrict__ wd1, bf16_t* __restrict__ wt2,
    bf16_t* __restrict__ cbb, float* __restrict__ cnorm,
    unsigned* __restrict__ hist, float* __restrict__ sse) {
  int id = blockIdx.x * 256 + threadIdx.x;                // grid 256 -> 65536
  int t = id >> 14, co = (id >> 7) & 127, ci = id & 127;
  wc2[id] = (bf16_t)ew2[(co * 128 + ci) * 4 + t];
  wd1[id] = (bf16_t)dw1[(ci * 128 + co) * 4 + (3 - t)];
  if (id < 8192) {
    int n = id >> 9, k = id & 511;
    int tap = k >> 7, c = k & 127;
    if (n < 12) {
      int nco = n >> 2, ph = (n >> 1) & 1, pw = n & 1;
      int off = (tap >> 1) * 8 + (tap & 1) * 2;           // 0,2,8,10
      wt2[id] = (bf16_t)dw2[c * 48 + nco * 16 + ph * 4 + pw + off];
    } else {
      wt2[id] = (bf16_t)0.f;
    }
    int c1 = id >> 6, k1 = id & 63;                       // wc1
    wc1[id] = (bf16_t)(k1 < 48 ? ew1[c1 * 48 + k1] : 0.f);
  }
  if (id < K_) {
    float s0 = 0.f;
    for (int d = 0; d < HID_; d += 4) {
      float4 v = *(const float4*)&cb[id * HID_ + d];
      bf16_t tt[4] = {(bf16_t)v.x, (bf16_t)v.y, (bf16_t)v.z, (bf16_t)v.w};
      *(ushort4*)&((ushort*)cbb)[id * HID_ + d] = *(ushort4*)tt;
      float f0 = (float)tt[0], f1 = (float)tt[1];
      float f2 = (float)tt[2], f3 = (float)tt[3];
      s0 += f0 * f0 + f1 * f1 + f2 * f2 + f3 * f3;
    }
    cnorm[id] = s0;
    hist[id] = 0u;
  }
  if (id == 0) *sse = 0.f;
}

// ---------------- conv1 (MFMA, fused transpose): x -> relu -> z1t bf16 ------
__global__ __launch_bounds__(256, 2) void conv1m_k(const float* __restrict__ x,
    const bf16_t* __restrict__ wc1, const float* __restrict__ bias,
    ushort* __restrict__ z1t) {
  __shared__ __align__(16) bf16_t as_[64 * 72];           // 9 KB
  __shared__ __align__(16) bf16_t bs_[128 * 72];          // 18 KB
  int b = blockIdx.x >> 4, rt = blockIdx.x & 15;          // grid = 64*16
  int tid = threadIdx.x, wv = tid >> 6, ln = tid & 63;
  const float* xb = x + (size_t)b * 12288;
  #pragma unroll
  for (int it = 0; it < 16; ++it) {
    int e = it * 256 + tid;                               // 4096 A entries
    int p = e >> 6, k = e & 63;
    float v = 0.f;
    if (k < 48) {
      int ci = k >> 4, kh = (k >> 2) & 3, kw = k & 3;
      int row = 2 * rt + (p >> 5); if (row > 30) row = 30; // clamp: discarded
      int col = p & 31;            if (col > 30) col = 30;
      v = xb[ci * 4096 + (2 * row + kh) * 64 + 2 * col + kw];
    }
    as_[p * 72 + k] = (bf16_t)v;
  }
  {
    const float4* wg = (const float4*)wc1;
    #pragma unroll
    for (int it = 0; it < 4; ++it) {
      int fi = it * 256 + tid;                            // 1024 f4s
      int co = fi >> 3, k8 = fi & 7;
      *(float4*)&bs_[co * 72 + k8 * 8] = wg[fi];
    }
  }
  __syncthreads();
  int q = ln >> 4, l = ln & 15;
  f32x4 acc8[8];
  #pragma unroll
  for (int c = 0; c < 8; ++c) acc8[c] = (f32x4){0.f, 0.f, 0.f, 0.f};
  bf16x8 af[2];
  #pragma unroll
  for (int kk = 0; kk < 2; ++kk)
    af[kk] = *(const bf16x8*)&as_[(wv * 16 + l) * 72 + kk * 32 + q * 8];
  #pragma unroll
  for (int cot = 0; cot < 8; ++cot) {
    #pragma unroll
    for (int kk = 0; kk < 2; ++kk) {
      bf16x8 bf = *(const bf16x8*)&bs_[(cot * 16 + l) * 72 + kk * 32 + q * 8];
      acc8[cot] = __builtin_amdgcn_mfma_f32_16x16x32_bf16(af[kk], bf,
                                                          acc8[cot], 0, 0, 0);
    }
  }
  #pragma unroll
  for (int cot = 0; cot < 8; ++cot) {
    int co = cot * 16 + l;
    float bv = bias[co];
    #pragma unroll
    for (int r = 0; r < 4; ++r) {
      int pos = wv * 16 + q * 4 + r;
      int prow = 2 * rt + (pos >> 5), pcol = pos & 31;
      if (prow < 31 && pcol < 31) {
        float v = fmaxf(acc8[cot][r] + bv, 0.f);
        bf16_t h = (bf16_t)v;
        z1t[((size_t)(b * 1024 + prow * 32 + pcol)) * 128 + co] = *(ushort*)&h;
      }
    }
  }
}

// ---------------- conv2 (MFMA, B in LDS): z1t -> relu -> zbuf bf16 only -----
__global__ __launch_bounds__(256, 2) void conv2m_k(const bf16_t* __restrict__ z1t,
    const bf16_t* __restrict__ wc2, const float* __restrict__ bias,
    ushort* __restrict__ zbuf) {
  __shared__ __align__(16) bf16_t as_[98 * 136];          // rows m+off, off<=33
  __shared__ __align__(16) bf16_t bs_[128 * 136];
  int blk = blockIdx.x;                                   // 64*15
  int b = blk / 15, rt = blk % 15;
  int tid = threadIdx.x, wv = tid >> 6, ln = tid & 63;
  const float4* src = (const float4*)(z1t + ((size_t)b * 1024 + rt * 64) * 128);
  #pragma unroll
  for (int s = 0; s < 7; ++s) {
    int f = s * 256 + tid;                                // 98*16 = 1568 f4s
    if (f < 1568) {
      int lp = f >> 4, c16 = f & 15;                      // max row 993 < 1024
      *(float4*)&as_[lp * 136 + c16 * 8] = src[f];
    }
  }
  int m = wv * 16 + (ln & 15), q = ln >> 4;
  f32x4 acc8[8];
  #pragma unroll
  for (int c = 0; c < 8; ++c) acc8[c] = (f32x4){0.f, 0.f, 0.f, 0.f};
  const float4* w4 = (const float4*)wc2;
  #pragma unroll
  for (int t = 0; t < 4; ++t) {
    __syncthreads();                                      // bs_ reuse (+A 1st)
    #pragma unroll
    for (int s = 0; s < 8; ++s) {
      int f = s * 256 + tid;
      int co = f >> 4, c16 = f & 15;
      *(float4*)&bs_[co * 136 + c16 * 8] = w4[t * 2048 + f];
    }
    __syncthreads();
    int off = (t >> 1) * 32 + (t & 1);                    // tap offset in pos
    bf16x8 af[4];
    #pragma unroll
    for (int kk = 0; kk < 4; ++kk)
      af[kk] = *(const bf16x8*)&as_[(m + off) * 136 + kk * 32 + q * 8];
    #pragma unroll
    for (int cot = 0; cot < 8; ++cot) {
      #pragma unroll
      for (int kk = 0; kk < 4; ++kk) {
        bf16x8 bf = *(const bf16x8*)&bs_[(cot * 16 + (ln & 15)) * 136 +
                                         kk * 32 + q * 8];
        acc8[cot] = __builtin_amdgcn_mfma_f32_16x16x32_bf16(af[kk], bf,
                                                            acc8[cot], 0, 0, 0);
      }
    }
  }
  #pragma unroll
  for (int cot = 0; cot < 8; ++cot) {
    int co = cot * 16 + (ln & 15);
    float bv = bias[co];
    #pragma unroll
    for (int r = 0; r < 4; ++r) {
      int mo = wv * 16 + q * 4 + r;
      int ocol = mo & 31;
      if (ocol < 30) {
        int orow = rt * 2 + (mo >> 5);                    // always < 30
        float v = fmaxf(acc8[cot][r] + bv, 0.f);
        bf16_t h = (bf16_t)v;
        zbuf[(size_t)(b * HID_ + co) * 900 + orow * 30 + ocol] = *(ushort*)&h;
      }
    }
  }
}

// ---------------- VQ phase 1 (MFMA 32x32x16): argmin + hist + fused SSE -----
// r28: REVERT to the r0 structure (session-best vq1 = 59.2 us; r21-r27
// restructures all measured slower or regressed the total) with ONE proven
// change: score-max argmin.  acc is initialized to -0.5*|c|^2 so
// score = z.c - 0.5|c|^2 falls out of the MFMA chain; candidate update is
// 1 cmp + 2 cndmask (3 VALU) vs the u64 monotone-map's 9.  Targets r0's
// largest busy term (VALUBusy 26.4%).  Tie semantics: ascending code scan
// with strict > keeps the smallest index; cross-lane/wave (score,idx)
// compares break ties to smaller idx (matches numpy argmin).  Correctness
// of this epilogue proven in r22/r25/r27 (3 passing rounds).
// Wave w: mtile=w&1, ntiles {(w>>1)*2, +1}.
// C/D: col(code)=lane&31, row=(reg&3)+8*(reg>>2)+4*(lane>>5)  [m74/m101].
__global__ __launch_bounds__(256, 2) void vq1_k(const bf16_t* __restrict__ zb,
    const bf16_t* __restrict__ cbb, const float* __restrict__ cnorm,
    int* __restrict__ idxArr, unsigned* __restrict__ hist,
    float* __restrict__ sse) {
  __shared__ __align__(16) bf16_t zs[64 * 136];           // 17 KB
  __shared__ __align__(16) bf16_t cbs[128 * 136];         // 34 KB
  __shared__ float cns[K_];                               // 4 KB (-0.5*|c|^2)
  __shared__ float redS[8][16];                           // 0.5 KB
  __shared__ int   redI[8][16];                           // 0.5 KB
  int n0 = blockIdx.x * 64;                               // 900 blocks
  int tid = threadIdx.x;
  int wv = tid >> 6, ln = tid & 63;
  {
    const float4* zg4 = (const float4*)(zb + (size_t)n0 * HID_);
    #pragma unroll
    for (int s = 0; s < 4; ++s) {
      int f = s * 256 + tid;
      int row = f >> 4, seg = f & 15;
      *(float4*)&zs[row * 136 + seg * 8] = zg4[f];
    }
    float4 cv = ((const float4*)cnorm)[tid];              // 1024 floats once
    cv.x *= -0.5f; cv.y *= -0.5f; cv.z *= -0.5f; cv.w *= -0.5f;
    ((float4*)cns)[tid] = cv;
  }
  __syncthreads();
  int mt = wv & 1, npair = wv >> 1;
  int lr = ln & 31, lh = ln >> 5;
  bf16x8 afr[8];                                          // hoisted A (K=128)
  #pragma unroll
  for (int ks = 0; ks < 8; ++ks)
    afr[ks] = *(const bf16x8*)&zs[(mt * 32 + lr) * 136 + ks * 16 + lh * 8];
  float bS[16];
  int   bI[16];
  #pragma unroll
  for (int r = 0; r < 16; ++r) { bS[r] = -3.4e38f; bI[r] = 0; }
  const float4* cg4 = (const float4*)cbb;
  for (int c0 = 0; c0 < K_; c0 += 128) {
    __syncthreads();                                      // cbs reuse
    #pragma unroll
    for (int s = 0; s < 8; ++s) {
      int f = s * 256 + tid;
      int code = f >> 4, seg = f & 15;
      *(float4*)&cbs[code * 136 + seg * 8] = cg4[(c0 + code) * 16 + seg];
    }
    __syncthreads();
    #pragma unroll
    for (int nt2 = 0; nt2 < 2; ++nt2) {
      int nt = npair * 2 + nt2;
      int code = c0 + nt * 32 + lr;                       // lane-fixed
      float hv = cns[code];
      f32x16 acc;
      #pragma unroll
      for (int r = 0; r < 16; ++r) acc[r] = hv;
      #pragma unroll
      for (int ks = 0; ks < 8; ++ks) {
        bf16x8 bfr = *(const bf16x8*)&cbs[(nt * 32 + lr) * 136 +
                                          ks * 16 + lh * 8];
        acc = __builtin_amdgcn_mfma_f32_32x32x16_bf16(afr[ks], bfr, acc,
                                                      0, 0, 0);
      }
      #pragma unroll
      for (int r = 0; r < 16; ++r)
        if (acc[r] > bS[r]) { bS[r] = acc[r]; bI[r] = code; }
    }
  }
  // reduce across the 32 lanes of each half (codes); rows stay per-lane
  #pragma unroll
  for (int r = 0; r < 16; ++r) {
    float s = bS[r]; int i = bI[r];
    #pragma unroll
    for (int o = 16; o > 0; o >>= 1) {
      float os = __shfl_xor(s, o, 64); int oi = __shfl_xor(i, o, 64);
      if (os > s || (os == s && oi < i)) { s = os; i = oi; }
    }
    bS[r] = s; bI[r] = i;
  }
  if (lr == 0) {
    #pragma unroll
    for (int r = 0; r < 16; ++r) {
      int e = (mt * 2 + npair) * 2 + lh;
      redS[e][r] = bS[r];
      redI[e][r] = bI[r];
    }
  }
  __syncthreads();
  if (tid < 64) {                                         // row = tid
    int fmt = tid >> 5, r32 = tid & 31;
    int half = (r32 >> 2) & 1;
    int reg = (r32 & 3) | (((r32 >> 3) & 3) << 2);
    int e0 = (fmt * 2 + 0) * 2 + half;
    int e1 = (fmt * 2 + 1) * 2 + half;
    float s0 = redS[e0][reg], s1 = redS[e1][reg];
    int i0 = redI[e0][reg], i1 = redI[e1][reg];
    bool t = (s1 > s0) || (s1 == s0 && i1 < i0);
    float sbest = t ? s1 : s0;
    int bi = t ? i1 : i0;
    idxArr[n0 + tid] = bi;
    atomicAdd(&hist[bi], 1u);
    // fused SSE: dist = |z'|^2 - 2*score (score includes -0.5|c|^2);
    // row tid in zs
    float zn = 0.f;
    #pragma unroll
    for (int s = 0; s < 16; ++s) {
      bf16x8 v = *(const bf16x8*)&zs[tid * 136 + s * 8];
      #pragma unroll
      for (int e = 0; e < 8; ++e) {
        float fv = (float)v[e];
        zn = fmaf(fv, fv, zn);
      }
    }
    float se = zn - 2.f * sbest;
    #pragma unroll
    for (int o = 32; o > 0; o >>= 1) se += __shfl_down(se, o, 64);
    if (tid == 0) atomicAdd(sse, se);
  }
}

// ---------------- tqz: tq gather + qt pad zero ------------------------------
__global__ __launch_bounds__(256) void tqz_k(const bf16_t* __restrict__ cbb,
    const int* __restrict__ idxArr, ushort* __restrict__ qt) {
  __shared__ ushort t[60 * 128];                          // 15 KB
  int bid = blockIdx.x, tid = threadIdx.x;
  if (bid < 960) {                                        // ---- tq ----
    int b = bid / 15, st = bid % 15;                      // 60-s tile
    int s0 = st * 60;
    #pragma unroll
    for (int it = 0; it < 8; ++it) {
      int task = it * 256 + tid;                          // sc*128 + c
      if (task < 1920) {
        int sc = task >> 7, c = task & 127;
        int f = b * 115200 + c * 900 + s0 + sc * 4;
        int n = f >> 7, d = f & 127;                      // d%4==0, no wrap
        int k = idxArr[n];
        ushort4 v = *(const ushort4*)((const ushort*)cbb + k * 128 + d);
        t[(sc * 4 + 0) * 128 + c] = v.x;
        t[(sc * 4 + 1) * 128 + c] = v.y;
        t[(sc * 4 + 2) * 128 + c] = v.z;
        t[(sc * 4 + 3) * 128 + c] = v.w;
      }
    }
    __syncthreads();
    #pragma unroll
    for (int it = 0; it < 4; ++it) {
      int task = it * 256 + tid;                          // sl*16 + c16
      if (task < 960) {
        int sl = task >> 4, c16 = task & 15;
        int s = s0 + sl;
        int h = s / 30, w = s - h * 30;
        int p = (h + 1) * 32 + (w + 1);
        *(uint4*)&qt[((size_t)(b * 1024 + p)) * 128 + c16 * 8] =
            *(uint4*)&t[sl * 128 + c16 * 8];
      }
    }
  } else {                                                // ---- qt pad ----
    int zb_ = (bid - 960) * 4;                            // 4 b's per block
    uint4 zz = {0u, 0u, 0u, 0u};
    for (int e = tid; e < 4 * 124 * 16; e += 256) {
      int bb = zb_ + e / (124 * 16);
      int rem = e % (124 * 16);
      int pe = rem >> 4, s16 = rem & 15;
      int p;
      if (pe < 32) p = pe;                                // row 0
      else if (pe < 64) p = 31 * 32 + (pe - 32);          // row 31
      else {
        int idx = pe - 64;                                // rows 1..30, c 0/31
        p = (1 + (idx >> 1)) * 32 + ((idx & 1) ? 31 : 0);
      }
      *(uint4*)&qt[((size_t)(bb * 1024 + p)) * 128 + s16 * 8] = zz;
    }
  }
}

// ---------------- convT1 (MFMA, B in LDS): qt -> relu -> yt bf16 ------------
__global__ __launch_bounds__(256, 2) void convt1m_k(const bf16_t* __restrict__ qt,
    const bf16_t* __restrict__ wd1, const float* __restrict__ bias,
    ushort* __restrict__ yt) {
  __shared__ __align__(16) bf16_t as_[98 * 136];
  __shared__ __align__(16) bf16_t bs_[128 * 136];
  int blk = blockIdx.x;                                   // 64*16
  int b = blk >> 4, rt = blk & 15;
  int tid = threadIdx.x, wv = tid >> 6, ln = tid & 63;
  {                                                       // fused pad zeroing
    uint4 zz = {0u, 0u, 0u, 0u};
    ushort* ytb = yt + (size_t)b * 1156 * 128;
    int nrows = (rt < 15) ? 2 : 1;                        // rt=15 owns row 31
    int r0 = 2 * rt + 1;
    for (int e = tid; e < nrows * 48; e += 256) {         // cols 0,32,33
      int rr = e / 48, rem = e % 48, cc = rem / 16, s16 = rem % 16;
      int col = (cc == 0) ? 0 : (cc == 1 ? 32 : 33);
      *(uint4*)&ytb[((size_t)((r0 + rr) * 34 + col)) * 128 + s16 * 8] = zz;
    }
    if (rt == 0)
      for (int e = tid; e < 34 * 16; e += 256)            // row 0
        *(uint4*)&ytb[((size_t)(e >> 4)) * 128 + (e & 15) * 8] = zz;
    if (rt == 15)
      for (int e = tid; e < 2 * 34 * 16; e += 256) {      // rows 32,33
        int rr = 32 + e / 544, rem = e % 544;
        *(uint4*)&ytb[((size_t)(rr * 34 + (rem >> 4))) * 128 + (rem & 15) * 8]
            = zz;
      }
  }
  const float4* src = (const float4*)(qt + (size_t)b * 1024 * 128);
  #pragma unroll
  for (int s = 0; s < 7; ++s) {
    int f = s * 256 + tid;                                // 1568 f4s
    if (f < 1568) {
      int lp = f >> 4, c16 = f & 15;
      int gr = rt * 64 + lp;
      if (gr > 1023) gr = 1023;                           // rt=15 guard
      *(float4*)&as_[lp * 136 + c16 * 8] = src[gr * 16 + c16];
    }
  }
  int m = wv * 16 + (ln & 15), q = ln >> 4;
  f32x4 acc8[8];
  #pragma unroll
  for (int c = 0; c < 8; ++c) acc8[c] = (f32x4){0.f, 0.f, 0.f, 0.f};
  const float4* w4 = (const float4*)wd1;
  #pragma unroll
  for (int t = 0; t < 4; ++t) {
    __syncthreads();
    #pragma unroll
    for (int s = 0; s < 8; ++s) {
      int f = s * 256 + tid;
      int co = f >> 4, c16 = f & 15;
      *(float4*)&bs_[co * 136 + c16 * 8] = w4[t * 2048 + f];
    }
    __syncthreads();
    int off = (t >> 1) * 32 + (t & 1);
    bf16x8 af[4];
    #pragma unroll
    for (int kk = 0; kk < 4; ++kk)
      af[kk] = *(const bf16x8*)&as_[(m + off) * 136 + kk * 32 + q * 8];
    #pragma unroll
    for (int cot = 0; cot < 8; ++cot) {
      #pragma unroll
      for (int kk = 0; kk < 4; ++kk) {
        bf16x8 bf = *(const bf16x8*)&bs_[(cot * 16 + (ln & 15)) * 136 +
                                         kk * 32 + q * 8];
        acc8[cot] = __builtin_amdgcn_mfma_f32_16x16x32_bf16(af[kk], bf,
                                                            acc8[cot], 0, 0, 0);
      }
    }
  }
  #pragma unroll
  for (int cot = 0; cot < 8; ++cot) {
    int co = cot * 16 + (ln & 15);
    float bv = bias[co];
    #pragma unroll
    for (int r = 0; r < 4; ++r) {
      int mo = wv * 16 + q * 4 + r;
      int orow = rt * 2 + (mo >> 5), ocol = mo & 31;
      if (orow < 31 && ocol < 31) {
        float v = fmaxf(acc8[cot][r] + bv, 0.f);
        bf16_t h = (bf16_t)v;
        yt[((size_t)b * 1156 + (orow + 1) * 34 + (ocol + 1)) * 128 + co] =
            *(ushort*)&h;
      }
    }
  }
}

// ---------------- convT2 (MFMA): yt -> out fp32, + fused finalize -----------
__global__ __launch_bounds__(256, 2) void convt2m_k(const bf16_t* __restrict__ yt,
    const bf16_t* __restrict__ wt2, const float* __restrict__ bias,
    const unsigned* __restrict__ hist, const float* __restrict__ sse,
    float* __restrict__ out) {
  __shared__ __align__(16) bf16_t as_[128 * 136];         // 34.8 KB
  __shared__ float redf[256];                             // 1 KB (fin branch)
  int b = blockIdx.x >> 4, rt = blockIdx.x & 15;          // grid = 64*16
  int tid = threadIdx.x, wv = tid >> 6, ln = tid & 63;
  const float4* src = (const float4*)(yt + ((size_t)b * 1156 + rt * 68) * 128);
  #pragma unroll
  for (int s = 0; s < 8; ++s) {
    int f = s * 256 + tid;
    int lp = f >> 4, c16 = f & 15;
    *(float4*)&as_[lp * 136 + c16 * 8] = src[f];
  }
  __syncthreads();
  int mloc = wv * 16 + (ln & 15), q = ln >> 4;
  int qh = mloc >> 5, qw = mloc & 31;                     // local quadrant pos
  int base = (qh + 1) * 34 + qw + 1;                      // in staged window
  f32x4 acc = {0.f, 0.f, 0.f, 0.f};
  #pragma unroll
  for (int kc = 0; kc < 16; ++kc) {
    int tap = kc >> 2;
    int toff = (tap & 1) + (tap >> 1) * 34;               // 0,1,34,35
    bf16x8 af = *(const bf16x8*)&as_[(base - toff) * 136 +
                                     (kc & 3) * 32 + q * 8];
    bf16x8 bf = *(const bf16x8*)&wt2[(size_t)(ln & 15) * 512 + kc * 32 + q * 8];
    acc = __builtin_amdgcn_mfma_f32_16x16x32_bf16(af, bf, acc, 0, 0, 0);
  }
  __syncthreads();                                        // as_ reads done
  float* bb = (float*)as_;                                // bounce: 64x16 f32
  #pragma unroll
  for (int r = 0; r < 4; ++r)
    bb[(wv * 16 + q * 4 + r) * 16 + (ln & 15)] = acc[r];
  __syncthreads();
  if (tid < 192) {
    int row_id = tid >> 4;                                // co*4 + ohoff
    int co = row_id >> 2, ohoff = row_id & 3;
    int qhl = ohoff >> 1, ph = ohoff & 1;
    float bv = bias[co];
    int ow0 = (tid & 15) * 4;
    float tmp[4];
    #pragma unroll
    for (int e = 0; e < 4; ++e) {
      int ow = ow0 + e;
      tmp[e] = bb[(qhl * 32 + (ow >> 1)) * 16 + co * 4 + ph * 2 + (ow & 1)]
               + bv;
    }
    *(float4*)&out[((size_t)(b * 3 + co)) * 4096 + (rt * 4 + ohoff) * 64 + ow0]
        = *(float4*)tmp;
  }
  if (blockIdx.x == 0) {                                  // ---- fused fin ----
    float e = 0.f;
    for (int k = tid; k < K_; k += 256) {
      float p = (float)hist[k] * (1.0f / (float)NROWS_);
      e += p * logf(p + 1e-10f);
    }
    redf[tid] = e;
    __syncthreads();
    #pragma unroll
    for (int t = 128; t > 0; t >>= 1) {
      if (tid < t) redf[tid] += redf[tid + t];
      __syncthreads();
    }
    if (tid == 0) {
      out[786432] = 1.25f * (*sse) * (1.0f / (float)NELEM_);
      out[786433] = expf(-redf[0]);
    }
  }
}

extern "C" void kernel_launch(void* const* d_in, const int* in_sizes, int n_in,
                              void* d_out, int out_size, void* d_ws,
                              size_t ws_size, hipStream_t stream) {
  (void)in_sizes; (void)n_in; (void)out_size; (void)ws_size;
  const float* x   = (const float*)d_in[0];
  const float* ew1 = (const float*)d_in[1];
  const float* eb1 = (const float*)d_in[2];
  const float* ew2 = (const float*)d_in[3];
  const float* eb2 = (const float*)d_in[4];
  const float* cb  = (const float*)d_in[5];
  const float* dw1 = (const float*)d_in[6];
  const float* db1 = (const float*)d_in[7];
  const float* dw2 = (const float*)d_in[8];
  const float* db2 = (const float*)d_in[9];
  float* out = (float*)d_out;
  char* ws = (char*)d_ws;

  // ws layout (~97.5 MB, aliased by liveness):
  //  [0, 35,684,352)            yt bf16 18.94 MB (pad zeroed in convt1m)
  //  [65,175,552, 81,985,536)   z1t bf16 (conv1m->conv2m) then qt bf16
  //  [81,985,536, 96,731,136)   zbuf bf16 (conv2m->vq1)
  //  [96,731,136 ..)  cbb | wc2 | wd1 | idxArr | hist | cnorm | sse | wt2 | wc1
  ushort*   yt    = (ushort*)(ws);
  bf16_t*   z1t   = (bf16_t*)(ws + 65175552);
  bf16_t*   qt    = (bf16_t*)(ws + 65175552);
  ushort*   zbuf  = (ushort*)(ws + 81985536);
  bf16_t*   cbb   = (bf16_t*)(ws + 96731136);
  bf16_t*   wc2   = (bf16_t*)(ws + 96993280);
  bf16_t*   wd1   = (bf16_t*)(ws + 97124352);
  int*      idxArr= (int*)(ws + 97255424);
  unsigned* hist  = (unsigned*)(ws + 97485824);
  float*    cnorm = (float*)(ws + 97489920);
  float*    sse   = (float*)(ws + 97494016);
  bf16_t*   wt2   = (bf16_t*)(ws + 97497088);
  bf16_t*   wc1   = (bf16_t*)(ws + 97513472);

  wprep_k<<<dim3(256), dim3(256), 0, stream>>>(ew1, ew2, dw1, dw2, cb,
                                               wc1, wc2, wd1, wt2,
                                               cbb, cnorm, hist, sse);
  conv1m_k<<<dim3(1024), dim3(256), 0, stream>>>(x, wc1, eb1, (ushort*)z1t);
  conv2m_k<<<dim3(960), dim3(256), 0, stream>>>(z1t, wc2, eb2, zbuf);
  vq1_k<<<dim3(900), dim3(256), 0, stream>>>((const bf16_t*)zbuf, cbb, cnorm,
                                             idxArr, hist, sse);
  tqz_k<<<dim3(976), dim3(256), 0, stream>>>(cbb, idxArr, (ushort*)qt);
  convt1m_k<<<dim3(1024), dim3(256), 0, stream>>>(qt, wd1, db1, yt);
  convt2m_k<<<dim3(1024), dim3(256), 0, stream>>>((const bf16_t*)yt, wt2, db2,
                                                  hist, sse, out);
}